// Round 3
// baseline (4812.575 us; speedup 1.0000x reference)
//
#include <hip/hip_runtime.h>

// Persistent-kernel Sinkhorn-Knopp (linear domain), P resident in LDS.
//   P = exp((mean+std*eps)/TAU) as bf16, 8 rows per block, 512 blocks x 512 thr,
//   2 blocks/CU (64 KiB LDS each) -> all co-resident; hand-rolled grid barrier.
// Per iter: row pass (block-local) -> col partials (8 MiB) -> barrier ->
//           reduce (block owns 8 cols) -> barrier.  2 grid syncs / iter.

constexpr int N    = 4096;
constexpr int IT   = 30;
constexpr int NBLK = 512;           // 8 rows per block
constexpr int TPB  = 512;           // 8 waves

typedef __attribute__((ext_vector_type(4))) unsigned short ushort4v;
typedef __attribute__((ext_vector_type(8))) unsigned short ushort8v;

__device__ inline float bf2f(unsigned int h) {
    union { unsigned int u; float f; } x; x.u = h << 16; return x.f;
}
__device__ inline unsigned short f2bf(float f) {
    union { float f; unsigned int u; } x; x.f = f;
    unsigned int r = x.u + 0x7FFFu + ((x.u >> 16) & 1u);   // round-nearest-even
    return (unsigned short)(r >> 16);
}

// ---- grid-wide barrier: generation counter, agent-scope atomics ------------
__device__ inline void grid_barrier(int* arrive, int* gen) {
    __syncthreads();
    if (threadIdx.x == 0) {
        __threadfence();   // release: wb dirty L2 so other XCDs can see our stores
        int my = __hip_atomic_load(gen, __ATOMIC_RELAXED, __HIP_MEMORY_SCOPE_AGENT);
        int prev = __hip_atomic_fetch_add(arrive, 1, __ATOMIC_ACQ_REL, __HIP_MEMORY_SCOPE_AGENT);
        if (prev == NBLK - 1) {
            __hip_atomic_store(arrive, 0, __ATOMIC_RELAXED, __HIP_MEMORY_SCOPE_AGENT);
            __hip_atomic_fetch_add(gen, 1, __ATOMIC_RELEASE, __HIP_MEMORY_SCOPE_AGENT);
        } else {
            long spins = 0;
            while (__hip_atomic_load(gen, __ATOMIC_RELAXED, __HIP_MEMORY_SCOPE_AGENT) == my) {
                __builtin_amdgcn_s_sleep(2);
                if (++spins > (1L << 20)) break;   // escape hatch: fail, don't hang
            }
        }
        __threadfence();   // acquire: invalidate L1/L2 so we read fresh data
    }
    __syncthreads();
}

__global__ __launch_bounds__(TPB, 4) void k_sinkhorn(
        const float* __restrict__ eps, const float* __restrict__ mean,
        const float* __restrict__ stdv, float* __restrict__ out,
        int* arrive, int* gen,
        float* __restrict__ vinv,      // [N]
        float* __restrict__ u_glob,    // [NBLK*8]
        float* __restrict__ wscratch,  // [NBLK*64]
        float* __restrict__ partial)   // [NBLK*N]
{
    __shared__ unsigned short P[8 * N];          // 65536 B (the whole LDS budget)
    const int blk  = blockIdx.x;
    const int t    = threadIdx.x;
    const int wave = t >> 6, lane = t & 63;
    const int row0 = blk * 8;

    // ---------------- init: P = exp((mean+std*eps)/2) for 8 contiguous rows --
    {
        const size_t base = (size_t)row0 * N;            // 32768 contiguous floats
        const float4* e4 = (const float4*)(eps  + base);
        const float4* m4 = (const float4*)(mean + base);
        const float4* s4 = (const float4*)(stdv + base);
        #pragma unroll 4
        for (int i = 0; i < 16; ++i) {
            int v = i * TPB + t;                         // 0..8191 float4s
            float4 e = e4[v], m = m4[v], s = s4[v];
            ushort4v p;
            p.x = f2bf(__expf((m.x + s.x * e.x) * 0.5f));
            p.y = f2bf(__expf((m.y + s.y * e.y) * 0.5f));
            p.z = f2bf(__expf((m.z + s.z * e.z) * 0.5f));
            p.w = f2bf(__expf((m.w + s.w * e.w) * 0.5f));
            *(ushort4v*)&P[(size_t)v * 4] = p;
        }
    }
    __syncthreads();

    for (int it = 1; it <= IT; ++it) {
        // ------------- row pass: wave w owns row w (block-local) -------------
        {
            const unsigned short* Pr = &P[wave * N];
            float s = 0.0f;
            if (it == 1) {                                // v == 1 on first iter
                #pragma unroll
                for (int k = 0; k < 16; ++k) {
                    int j = k * 64 + lane;
                    ushort4v p = *(const ushort4v*)&Pr[j * 4];
                    s += (bf2f(p.x) + bf2f(p.y)) + (bf2f(p.z) + bf2f(p.w));
                }
            } else {
                const float4* vv = (const float4*)vinv;
                #pragma unroll
                for (int k = 0; k < 16; ++k) {
                    int j = k * 64 + lane;
                    ushort4v p = *(const ushort4v*)&Pr[j * 4];
                    float4 v4 = vv[j];
                    s += bf2f(p.x) * v4.x + bf2f(p.y) * v4.y
                       + bf2f(p.z) * v4.z + bf2f(p.w) * v4.w;
                }
            }
            #pragma unroll
            for (int off = 32; off; off >>= 1) s += __shfl_xor(s, off, 64);
            if (lane == 0) {
                float u = __builtin_amdgcn_rcpf(s);
                __hip_atomic_store(&u_glob[blk * 8 + wave], u,
                                   __ATOMIC_RELEASE, __HIP_MEMORY_SCOPE_WORKGROUP);
            }
        }
        __syncthreads();

        // ------------- col pass: thread t -> cols [8t, 8t+8), all 8 rows -----
        {
            float acc[8] = {0, 0, 0, 0, 0, 0, 0, 0};
            #pragma unroll
            for (int r = 0; r < 8; ++r) {
                float u = __hip_atomic_load(&u_glob[blk * 8 + r],
                                            __ATOMIC_ACQUIRE, __HIP_MEMORY_SCOPE_WORKGROUP);
                ushort8v p = *(const ushort8v*)&P[r * N + t * 8];
                #pragma unroll
                for (int k = 0; k < 8; ++k) acc[k] += bf2f(p[k]) * u;
            }
            float4* dst = (float4*)&partial[(size_t)blk * N + t * 8];
            float4 a = {acc[0], acc[1], acc[2], acc[3]};
            float4 b = {acc[4], acc[5], acc[6], acc[7]};
            dst[0] = a;
            dst[1] = b;
        }

        grid_barrier(arrive, gen);                       // A: partials visible

        // ------------- reduce: block owns cols [8*blk, 8*blk+8) --------------
        {
            const int col   = blk * 8 + (t & 7);
            const int chunk = t >> 3;                    // 0..63
            float s = 0.0f;
            #pragma unroll
            for (int bi = 0; bi < 8; ++bi)
                s += partial[(size_t)(chunk * 8 + bi) * N + col];
            s += __shfl_xor(s, 8, 64);
            s += __shfl_xor(s, 16, 64);
            s += __shfl_xor(s, 32, 64);                  // lanes 0..7: per-wave sums
            if (lane < 8)
                __hip_atomic_store(&wscratch[blk * 64 + wave * 8 + lane], s,
                                   __ATOMIC_RELEASE, __HIP_MEMORY_SCOPE_WORKGROUP);
        }
        __syncthreads();
        if (t < 8) {
            float s = 0.0f;
            #pragma unroll
            for (int w = 0; w < 8; ++w)
                s += __hip_atomic_load(&wscratch[blk * 64 + w * 8 + t],
                                       __ATOMIC_ACQUIRE, __HIP_MEMORY_SCOPE_WORKGROUP);
            vinv[blk * 8 + t] = __builtin_amdgcn_rcpf(s);
        }

        grid_barrier(arrive, gen);                       // B: vinv visible
    }

    // ---------------- final: out[i][j] = u_i * P[i][j] * vinv[j] -------------
    {
        const float4* vv = (const float4*)vinv;
        const float u = __hip_atomic_load(&u_glob[blk * 8 + wave],
                                          __ATOMIC_ACQUIRE, __HIP_MEMORY_SCOPE_WORKGROUP);
        float* orow = out + (size_t)(row0 + wave) * N;
        const unsigned short* Pr = &P[wave * N];
        #pragma unroll
        for (int k = 0; k < 16; ++k) {
            int j = k * 64 + lane;
            ushort4v p = *(const ushort4v*)&Pr[j * 4];
            float4 v4 = vv[j];
            float4 o;
            o.x = bf2f(p.x) * u * v4.x;
            o.y = bf2f(p.y) * u * v4.y;
            o.z = bf2f(p.z) * u * v4.z;
            o.w = bf2f(p.w) * u * v4.w;
            *(float4*)&orow[j * 4] = o;
        }
    }
}

// ------------------------------------------------------------- launcher -----
extern "C" void kernel_launch(void* const* d_in, const int* in_sizes, int n_in,
                              void* d_out, int out_size, void* d_ws, size_t ws_size,
                              hipStream_t stream) {
    const float* eps  = (const float*)d_in[0];
    const float* mean = (const float*)d_in[1];
    const float* stdv = (const float*)d_in[2];
    float* out = (float*)d_out;

    char* ws = (char*)d_ws;
    int*   arrive   = (int*)ws;                         // @0
    int*   gen      = (int*)(ws + 4);                   // @4
    float* vinv     = (float*)(ws + 256);               // 16 KB
    float* u_glob   = vinv + N;                         // 16 KB
    float* wscratch = u_glob + NBLK * 8;                // 128 KB
    float* partial  = (float*)(ws + (256 << 10));       // 8 MiB @ 256 KiB offset

    hipMemsetAsync(ws, 0, 256, stream);                 // zero barrier state
    k_sinkhorn<<<NBLK, TPB, 0, stream>>>(eps, mean, stdv, out,
                                         arrive, gen, vinv, u_glob, wscratch, partial);
}